// Round 16
// baseline (76.447 us; speedup 1.0000x reference)
//
#include <hip/hip_runtime.h>
#include <math.h>

// HierarchicalPooling collapsed pipeline, round 16.
// N=32768, D=256, S=4, H=8, DH=32, CS=3276, C=11.
// R15: 60.6us; kbd10 ~28-32us, ~4x its HBM floor, latency-exposed at 2.03
// co-resident blocks/CU. R16: 32-row chunks, 256-thr blocks -> 1031 blocks
// (4.03/CU co-resident, 4 independent stage/compute chains per CU).
// Pass-2 K=32: single MFMA per tile, same tr-read pattern (R13-verified,
// offsets rescaled). All other kernels byte-identical to R15.

namespace {
constexpr int N    = 32768;
constexpr int CS   = 3276;
constexpr int CPC  = 103;               // 32-row chunks per full cluster
constexpr int NB   = CPC*10 + 1;        // 1031 blocks

// ws layout (float offsets); total ~17.3 MB
constexpr size_t CQ_OFF   = 0;                               // 32
constexpr size_t WQBF_OFF = 32;                              // 1024 uint4 B-fragments
constexpr size_t PART_OFF = WQBF_OFF + 4096;                 // NB chunk partials, bf16 [32 sh][256 d]
constexpr size_t PS_OFF   = PART_OFF + (size_t)NB*4096;      // 11*32 sum-exp (atomic)
constexpr size_t XW_OFF   = PS_OFF + 352;                    // 11*8192 normalized xw
constexpr size_t PL_OFF   = XW_OFF + 90112;                  // 11*1024 pooled
constexpr size_t OL_OFF   = PL_OFF + 11264;                  // 11*1024 out rows
constexpr size_t HP_OFF   = OL_OFF + 11264;                  // 11*4*256 Wf1 partials
constexpr size_t FP_OFF   = HP_OFF + 11264;                  // 11*4*256 Wf2 partials
}

typedef __attribute__((ext_vector_type(8))) short short8;
typedef __attribute__((ext_vector_type(4))) float f32x4;

__device__ __forceinline__ unsigned f2bf(float f){    // f32 -> bf16 bits, RNE
  unsigned u = __float_as_uint(f);
  unsigned r = u + 0x7FFFu + ((u >> 16) & 1u);
  return r >> 16;
}

// ---- KA: wq rows -> bf16 B-fragments (packed via LDS); cq; PS zero. (R10-proven)
__global__ __launch_bounds__(256) void ka(const float* __restrict__ Wk, const float* __restrict__ bk,
                                          const float* __restrict__ pq, float* __restrict__ ws){
  int b = blockIdx.x, t = threadIdx.x;
  const float scale = 0.17677669529663688f;   // 32^-0.5
  if (b < 32){
    __shared__ float row[256];
    int s = b >> 3, h = b & 7;
    const float* wrow = Wk + ((size_t)s<<16) + (size_t)t*256 + h*32;
    const float* q = pq + (s*8 + h)*32;
    float a = 0.f;
#pragma unroll
    for (int j=0;j<32;j++) a = fmaf(wrow[j], q[j], a);
    row[t] = a*scale;
    __syncthreads();
    if (t < 32){
      int ks = t & 7, kg2 = t >> 3;
      const float* src = row + ks*32 + kg2*8;
      uint4 p;
      p.x = f2bf(src[0]) | (f2bf(src[1]) << 16);
      p.y = f2bf(src[2]) | (f2bf(src[3]) << 16);
      p.z = f2bf(src[4]) | (f2bf(src[5]) << 16);
      p.w = f2bf(src[6]) | (f2bf(src[7]) << 16);
      int Nt = b >> 4, l15b = b & 15;
      ((uint4*)(ws + WQBF_OFF))[(size_t)(Nt*8 + ks)*64 + l15b + 16*kg2] = p;
    }
  } else {
    if (t < 32){
      int s = t >> 3, h = t & 7;
      const float* br = bk + s*256 + h*32;
      const float* q = pq + t*32;
      float a = 0.f;
#pragma unroll
      for (int j=0;j<32;j++) a = fmaf(br[j], q[j], a);
      ws[CQ_OFF + t] = a*scale;
    }
    for (int i = t; i < 352; i += 256) ws[PS_OFF + i] = 0.f;   // zero atomic targets
  }
}

// ---- KBD11: MFMA scores + exp + PS atomics + MFMA xw chunk partials.
// 1031 blocks x 256 threads; 32-row bf16 tile; 4 co-resident blocks/CU.
__global__ __launch_bounds__(256,4) void kbd11(const float* __restrict__ x, float* __restrict__ ws){
  int b = blockIdx.x, t = threadIdx.x;
  int c  = (b < 1030) ? (b / CPC) : 10;
  int wi = (b < 1030) ? (b % CPC) : 0;
  int n0 = c*CS + wi*32;
  int n1 = min(n0 + 32, min((c+1)*CS, N));
  int cnt = n1 - n0;                    // 32, 12 (cluster tails), or 8 (cluster 10)

  __shared__ __align__(16) unsigned short xtb[32*264]; // 16.9KB bf16 tile, row stride 528B
  __shared__ __align__(16) unsigned short swT[32*72];  // 4.6KB bf16 weights [sh][j], stride 144B
  __shared__ float psb[8*32];

  int wv = t >> 6, lane = t & 63;
  int l15 = lane & 15, kg = lane >> 4;
  int Mt = wv & 1, Nt = wv >> 1;        // pass-1 tile roles (2x2 tiles, 4 waves)
  int arow = Mt*16 + l15;
  uint4 bfr[8];
  const uint4* WQBF4 = (const uint4*)(ws + WQBF_OFF);
#pragma unroll
  for (int ks=0; ks<8; ++ks) bfr[ks] = WQBF4[(size_t)(Nt*8 + ks)*64 + lane];
  float cqv = ws[CQ_OFF + Nt*16 + l15];
  int shc = Nt*16 + l15;

  // stage 32 rows as bf16; rows >= N zero-filled (NaN-safe for pass2 MFMA)
  const float4* X4 = (const float4*)x;
#pragma unroll
  for (int k=0;k<8;k++){
    int f = t + k*256;
    int j = f >> 6, c4 = f & 63;
    float4 v = (n0 + j < N) ? X4[(size_t)(n0+j)*64 + c4] : make_float4(0.f,0.f,0.f,0.f);
    uint2 p;
    p.x = f2bf(v.x) | (f2bf(v.y) << 16);
    p.y = f2bf(v.z) | (f2bf(v.w) << 16);
    *(uint2*)(xtb + j*264 + c4*4) = p;
  }
  __syncthreads();

  // ---- pass 1: scores via 8x mfma_f32_16x16x32_bf16 per wave (one 16x16 tile)
  f32x4 acc1 = {0.f, 0.f, 0.f, 0.f};
#pragma unroll
  for (int ks=0; ks<8; ++ks){
    union { uint4 q; short8 v; } A, B;
    A.q = *(const uint4*)(xtb + arow*264 + ks*32 + kg*8);
    B.q = bfr[ks];
    acc1 = __builtin_amdgcn_mfma_f32_16x16x32_bf16(A.v, B.v, acc1, 0, 0, 0);
  }
  // epilogue: weights (bf16) -> swT[sh][j]; zero for j >= cnt; chunk sums.
  // C layout: col(sh)=lane&15, row(j)=kg*4+reg.
  {
    float ev[4];
    float s4 = 0.f;
#pragma unroll
    for (int r=0;r<4;r++){
      int jl = Mt*16 + kg*4 + r;
      float e = (jl < cnt) ? __expf(acc1[r] + cqv) : 0.f;
      ev[r] = e; s4 += e;
    }
    uint2 wp;
    wp.x = f2bf(ev[0]) | (f2bf(ev[1]) << 16);
    wp.y = f2bf(ev[2]) | (f2bf(ev[3]) << 16);
    *(uint2*)(swT + (size_t)shc*72 + Mt*16 + kg*4) = wp;
    psb[(Mt*4 + kg)*32 + shc] = s4;
  }
  __syncthreads();
  if (t < 32){
    float S = 0.f;
#pragma unroll
    for (int k=0;k<8;k++) S += psb[k*32 + t];
    unsafeAtomicAdd(ws + PS_OFF + (size_t)c*32 + t, S);
  }

  // ---- pass 2: O[sh][d] = sum_j w[j][sh]*x[j][d] via MFMA (K=32, 1 MFMA/tile).
  // wave: Mt2 = wv&1 (sh-tile), Dq = wv>>1 (8 d-tiles dt = Dq*8+i).
  int Mt2 = wv & 1, Dq = wv >> 1;
  union FR { uint4 q; short8 v; };
  FR a0;   // A: lane m = l15 (sh), k = kg*8 + e (j)
  a0.q = *(const uint4*)(swT + (size_t)(Mt2*16 + l15)*72 + kg*8);
  // B via HW transpose read (R13-verified pattern, rescaled: d-base = Dq*128 d = 256B)
  unsigned xb = (unsigned)(size_t)&xtb[0];
  unsigned va = xb + (unsigned)(kg*4224 + (l15>>2)*528 + (l15&3)*8 + Dq*256);
  unsigned long long tr[8][2];
#pragma unroll
  for (int i=0;i<8;i++){
    asm volatile("ds_read_b64_tr_b16 %0, %2 offset:%c3\n\t"
                 "ds_read_b64_tr_b16 %1, %2 offset:%c4"
                 : "=v"(tr[i][0]), "=v"(tr[i][1])
                 : "v"(va), "i"(i*32), "i"(i*32 + 2112));
  }
  asm volatile("s_waitcnt lgkmcnt(0)" ::: "memory");
  __builtin_amdgcn_sched_barrier(0);
  f32x4 o[8] = {{0.f,0.f,0.f,0.f},{0.f,0.f,0.f,0.f},{0.f,0.f,0.f,0.f},{0.f,0.f,0.f,0.f},
                {0.f,0.f,0.f,0.f},{0.f,0.f,0.f,0.f},{0.f,0.f,0.f,0.f},{0.f,0.f,0.f,0.f}};
#pragma unroll
  for (int i=0;i<8;i++){
    FR Bf;
    Bf.q.x = (unsigned)(tr[i][0] & 0xffffffffULL);
    Bf.q.y = (unsigned)(tr[i][0] >> 32);
    Bf.q.z = (unsigned)(tr[i][1] & 0xffffffffULL);
    Bf.q.w = (unsigned)(tr[i][1] >> 32);
    o[i] = __builtin_amdgcn_mfma_f32_16x16x32_bf16(a0.v, Bf.v, o[i], 0, 0, 0);
  }
  // store partials as bf16: C layout col(d)=l15, row(sh)=kg*4+r
  unsigned short* pr = (unsigned short*)(ws + PART_OFF) + (size_t)b*8192;
#pragma unroll
  for (int i=0;i<8;i++){
    int dcol = Dq*128 + i*16 + l15;
#pragma unroll
    for (int r=0;r<4;r++)
      pr[(size_t)(Mt2*16 + kg*4 + r)*256 + dcol] = (unsigned short)f2bf(o[i][r]);
  }
}

// ---- KE2: sum bf16 chunk partials (f32 accum) / PS -> xw[c][sh][d]. 352 blocks.
__global__ __launch_bounds__(256) void ke2(float* __restrict__ ws){
  int b = blockIdx.x, t = threadIdx.x;
  int c = b >> 5, sh = b & 31;
  int nch = (c < 10) ? CPC : 1;
  int cb  = (c < 10) ? c*CPC : 1030;
  float rden = 1.0f / ws[PS_OFF + (size_t)c*32 + sh];
  const unsigned short* part = (const unsigned short*)(ws + PART_OFF) + (size_t)sh*256 + t;
  float a = 0.f;
  for (int k=0;k<nch;k++)
    a += __uint_as_float(((unsigned)part[(size_t)(cb+k)*8192]) << 16);
  ws[XW_OFF + (size_t)c*8192 + (size_t)sh*256 + t] = a * rden;
}

// ---- KP: pooled per (c,s,eq). 176 blocks (R7-proven).
__global__ __launch_bounds__(256) void kp(float* __restrict__ ws,
    const float* __restrict__ Wv, const float* __restrict__ bv){
  int b = blockIdx.x; int c = b >> 4, rem = b & 15, s = rem >> 2, eq = rem & 3;
  int t = threadIdx.x, e64 = t & 63, dq = t >> 6;
  int e = eq*64 + e64, h = e >> 5;
  const float* xr = ws + XW_OFF + (size_t)c*8192 + (size_t)(s*8 + h)*256 + dq*64;
  const float* wv = Wv + (size_t)s*65536 + (size_t)(dq*64)*256 + e;
  float a = 0.f;
#pragma unroll 8
  for (int d=0; d<64; ++d) a = fmaf(wv[(size_t)d*256], xr[d], a);
  __shared__ float red[4][64];
  red[dq][e64] = a;
  __syncthreads();
  if (t < 64){
    float rcnt = (c < 10) ? (1.0f/(float)CS) : 0.125f;
    float p = (red[0][t]+red[1][t]+red[2][t]+red[3][t] + bv[s*256 + eq*64 + t]) * rcnt;
    ws[PL_OFF + (size_t)c*1024 + s*256 + eq*64 + t] = p;
  }
}

// ---- KO: out per (c,s,eq) = pooled @ Wo + bo. 176 blocks (R7-proven).
__global__ __launch_bounds__(256) void ko(float* __restrict__ ws,
    const float* __restrict__ Wo, const float* __restrict__ bo){
  int b = blockIdx.x; int c = b >> 4, rem = b & 15, s = rem >> 2, eq = rem & 3;
  int t = threadIdx.x, e64 = t & 63, dq = t >> 6;
  int e = eq*64 + e64;
  const float* pr = ws + PL_OFF + (size_t)c*1024 + s*256 + dq*64;
  const float* wo = Wo + (size_t)s*65536 + (size_t)(dq*64)*256 + e;
  float a = 0.f;
#pragma unroll 8
  for (int d=0; d<64; ++d) a = fmaf(wo[(size_t)d*256], pr[d], a);
  __shared__ float red[4][64];
  red[dq][e64] = a;
  __syncthreads();
  if (t < 64)
    ws[OL_OFF + (size_t)c*1024 + s*256 + eq*64 + t] =
      red[0][t]+red[1][t]+red[2][t]+red[3][t] + bo[s*256 + eq*64 + t];
}

// ---- KF1: h partials: block (c, fq, kq). 176 blocks (R7-proven).
__global__ __launch_bounds__(256) void kf1(const float* __restrict__ Wf1, float* __restrict__ ws){
  int b = blockIdx.x; int c = b >> 4, fq = (b >> 2) & 3, kq = b & 3;
  int t = threadIdx.x, f64 = t & 63, ks = t >> 6;
  const float* ol = ws + OL_OFF + (size_t)c*1024 + kq*256 + ks*64;
  const float* wf = Wf1 + (size_t)(kq*256 + ks*64)*256 + fq*64 + f64;
  float a = 0.f;
#pragma unroll 8
  for (int i=0; i<64; ++i) a = fmaf(wf[(size_t)i*256], ol[i], a);
  __shared__ float red[4][64];
  red[ks][f64] = a;
  __syncthreads();
  if (t < 64)
    ws[HP_OFF + (size_t)(c*4 + kq)*256 + fq*64 + t] = red[0][t]+red[1][t]+red[2][t]+red[3][t];
}

// ---- KF2B: (LN+GELU recomputed in-block from HP) -> Wf2 partials. 176 blocks (R11-proven).
__global__ __launch_bounds__(256) void kf2b(const float* __restrict__ Wf2, float* __restrict__ ws,
    const float* __restrict__ bf1, const float* __restrict__ lng, const float* __restrict__ lnb){
  int b = blockIdx.x; int c = b >> 4, gq = (b >> 2) & 3, kq = b & 3;
  int t = threadIdx.x;
  __shared__ float hl[256];
  __shared__ float rs1[4], rs2[4];
  float hacc = bf1[t];
#pragma unroll
  for (int q=0;q<4;q++) hacc += ws[HP_OFF + (size_t)(c*4+q)*256 + t];
  float s1 = hacc, s2v = hacc*hacc;
  for (int off=32; off>0; off>>=1){ s1 += __shfl_down(s1, off, 64); s2v += __shfl_down(s2v, off, 64); }
  int wid = t>>6, lane = t&63;
  if (lane==0){ rs1[wid]=s1; rs2[wid]=s2v; }
  __syncthreads();
  float S1 = rs1[0]+rs1[1]+rs1[2]+rs1[3];
  float S2 = rs2[0]+rs2[1]+rs2[2]+rs2[3];
  float mu = S1*(1.0f/256.0f);
  float var = S2*(1.0f/256.0f) - mu*mu;
  float rsig = rsqrtf(var + 1e-5f);
  float hn = (hacc - mu)*rsig*lng[t] + lnb[t];
  hl[t] = 0.5f*hn*(1.0f + erff(hn*0.70710678118654752f));   // exact GELU
  __syncthreads();
  int g64 = t & 63, ks = t >> 6;
  const float* hh = hl + kq*64 + ks*16;
  const float* wf = Wf2 + (size_t)(kq*64 + ks*16)*256 + gq*64 + g64;
  float a = 0.f;
#pragma unroll
  for (int i=0; i<16; ++i) a = fmaf(wf[(size_t)i*256], hh[i], a);
  __shared__ float red[4][64];
  red[ks][g64] = a;
  __syncthreads();
  if (t < 64)
    ws[FP_OFF + (size_t)(c*4 + kq)*256 + gq*64 + t] = red[0][t]+red[1][t]+red[2][t]+red[3][t];
}

// ---- KBC2: sum Wf2 partials + bf2 once per block, broadcast. 8192 blocks (R7-proven).
__global__ __launch_bounds__(256) void kbc2(const float* __restrict__ ws, float4* __restrict__ out,
                                            const float* __restrict__ bf2){
  unsigned bidx = blockIdx.x, t = threadIdx.x;
  unsigned idx = bidx*256u + t;
  unsigned c = (bidx*4u) / (unsigned)CS;   // 3276 % 4 == 0 -> one cluster per block
  __shared__ float4 row[64];
  if (t < 64){
    const float4* FP4 = (const float4*)(ws + FP_OFF);
    float4 s0 = FP4[(c*4+0)*64 + t];
    float4 s1 = FP4[(c*4+1)*64 + t];
    float4 s2 = FP4[(c*4+2)*64 + t];
    float4 s3 = FP4[(c*4+3)*64 + t];
    float4 bb = ((const float4*)bf2)[t];
    row[t] = make_float4(s0.x+s1.x+s2.x+s3.x+bb.x, s0.y+s1.y+s2.y+s3.y+bb.y,
                         s0.z+s1.z+s2.z+s3.z+bb.z, s0.w+s1.w+s2.w+s3.w+bb.w);
  }
  __syncthreads();
  out[idx] = row[t & 63u];
}

extern "C" void kernel_launch(void* const* d_in, const int* in_sizes, int n_in,
                              void* d_out, int out_size, void* d_ws, size_t ws_size,
                              hipStream_t stream) {
  const float* x   = (const float*)d_in[0];
  // d_in[1] edge_index, d_in[2] batch: unused by the reference computation
  const float* Wk  = (const float*)d_in[3];
  const float* bk  = (const float*)d_in[4];
  const float* Wv  = (const float*)d_in[5];
  const float* bv  = (const float*)d_in[6];
  const float* Wo  = (const float*)d_in[7];
  const float* bo  = (const float*)d_in[8];
  const float* pq  = (const float*)d_in[9];
  const float* Wf1 = (const float*)d_in[10];
  const float* bf1 = (const float*)d_in[11];
  const float* lng = (const float*)d_in[12];
  const float* lnb = (const float*)d_in[13];
  const float* Wf2 = (const float*)d_in[14];
  const float* bf2 = (const float*)d_in[15];
  float* ws = (float*)d_ws;
  float4* out = (float4*)d_out;

  hipLaunchKernelGGL(ka,    dim3(33),   dim3(256), 0, stream, Wk, bk, pq, ws);
  hipLaunchKernelGGL(kbd11, dim3(NB),   dim3(256), 0, stream, x, ws);
  hipLaunchKernelGGL(ke2,   dim3(352),  dim3(256), 0, stream, ws);
  hipLaunchKernelGGL(kp,    dim3(176),  dim3(256), 0, stream, ws, Wv, bv);
  hipLaunchKernelGGL(ko,    dim3(176),  dim3(256), 0, stream, ws, Wo, bo);
  hipLaunchKernelGGL(kf1,   dim3(176),  dim3(256), 0, stream, Wf1, ws);
  hipLaunchKernelGGL(kf2b,  dim3(176),  dim3(256), 0, stream, Wf2, ws, bf1, lng, lnb);
  hipLaunchKernelGGL(kbc2,  dim3(8192), dim3(256), 0, stream, ws, out, bf2);
}

// Round 17
// 60.690 us; speedup vs baseline: 1.2596x; 1.2596x over previous
//
#include <hip/hip_runtime.h>
#include <math.h>

// HierarchicalPooling collapsed pipeline, round 17 (= R15 verbatim, the
// measured best: 60.6us, absmax 1.95e-3).
// N=32768, D=256, S=4, H=8, DH=32, CS=3276, C=11.
// Structure: ka (wq->bf16 MFMA B-frags, cq, PS zero) -> kbd10 (64-row bf16
// LDS tile; pass1 scores via MFMA; exp; PS atomics; pass2 xw via MFMA with
// ds_read_b64_tr_b16 transpose reads; bf16 chunk partials) -> ke2 (reduce/
// normalize) -> kp -> ko -> kf1 -> kf2b (LN+GELU in-block) -> kbc2 (broadcast).
// Lessons locked in: LDS-staged tiles beat global streaming (R11); 176-block
// split chain beats fused narrow kernels (R6/R8/R14); 64-row chunks at 521
// blocks beat both 128-row/261 (R10) and 32-row/1031 (R16); bf16 partials
// save ~1.2us (R15); MFMA + tr_b16 pass-2 saves ~7.6us (R13).

namespace {
constexpr int N   = 32768;
constexpr int CS  = 3276;
constexpr int CPC = 52;                // 64-node chunks per full cluster
constexpr int NB  = CPC*10 + 1;        // 521 blocks

// ws layout (float offsets); total ~9.1 MB
constexpr size_t CQ_OFF   = 0;                               // 32
constexpr size_t WQBF_OFF = 32;                              // 1024 uint4 B-fragments
constexpr size_t PART_OFF = WQBF_OFF + 4096;                 // NB*8192 bf16 chunk partials (NB*4096 floats)
constexpr size_t PS_OFF   = PART_OFF + (size_t)NB*4096;      // 11*32 sum-exp (atomic)
constexpr size_t XW_OFF   = PS_OFF + 352;                    // 11*8192 normalized xw
constexpr size_t PL_OFF   = XW_OFF + 90112;                  // 11*1024 pooled
constexpr size_t OL_OFF   = PL_OFF + 11264;                  // 11*1024 out rows
constexpr size_t HP_OFF   = OL_OFF + 11264;                  // 11*4*256 Wf1 partials
constexpr size_t FP_OFF   = HP_OFF + 11264;                  // 11*4*256 Wf2 partials
}

typedef __attribute__((ext_vector_type(8))) short short8;
typedef __attribute__((ext_vector_type(4))) float f32x4;

__device__ __forceinline__ unsigned f2bf(float f){    // f32 -> bf16 bits, RNE
  unsigned u = __float_as_uint(f);
  unsigned r = u + 0x7FFFu + ((u >> 16) & 1u);
  return r >> 16;
}

// ---- KA: wq rows -> bf16 B-fragments (packed via LDS); cq; PS zero. (R10-proven)
__global__ __launch_bounds__(256) void ka(const float* __restrict__ Wk, const float* __restrict__ bk,
                                          const float* __restrict__ pq, float* __restrict__ ws){
  int b = blockIdx.x, t = threadIdx.x;
  const float scale = 0.17677669529663688f;   // 32^-0.5
  if (b < 32){
    __shared__ float row[256];
    int s = b >> 3, h = b & 7;
    const float* wrow = Wk + ((size_t)s<<16) + (size_t)t*256 + h*32;
    const float* q = pq + (s*8 + h)*32;
    float a = 0.f;
#pragma unroll
    for (int j=0;j<32;j++) a = fmaf(wrow[j], q[j], a);
    row[t] = a*scale;
    __syncthreads();
    if (t < 32){
      int ks = t & 7, kg2 = t >> 3;
      const float* src = row + ks*32 + kg2*8;
      uint4 p;
      p.x = f2bf(src[0]) | (f2bf(src[1]) << 16);
      p.y = f2bf(src[2]) | (f2bf(src[3]) << 16);
      p.z = f2bf(src[4]) | (f2bf(src[5]) << 16);
      p.w = f2bf(src[6]) | (f2bf(src[7]) << 16);
      int Nt = b >> 4, l15b = b & 15;
      ((uint4*)(ws + WQBF_OFF))[(size_t)(Nt*8 + ks)*64 + l15b + 16*kg2] = p;
    }
  } else {
    if (t < 32){
      int s = t >> 3, h = t & 7;
      const float* br = bk + s*256 + h*32;
      const float* q = pq + t*32;
      float a = 0.f;
#pragma unroll
      for (int j=0;j<32;j++) a = fmaf(br[j], q[j], a);
      ws[CQ_OFF + t] = a*scale;
    }
    for (int i = t; i < 352; i += 256) ws[PS_OFF + i] = 0.f;   // zero atomic targets
  }
}

// ---- KBD10: MFMA scores + exp + PS atomics + MFMA xw chunk partials (bf16 store).
__global__ __launch_bounds__(512,4) void kbd10(const float* __restrict__ x, float* __restrict__ ws){
  int b = blockIdx.x, t = threadIdx.x;
  int c  = (b < 520) ? (b / CPC) : 10;
  int wi = (b < 520) ? (b % CPC) : 0;
  int n0 = c*CS + wi*64;
  int n1 = min(n0 + 64, min((c+1)*CS, N));
  int cnt = n1 - n0;                    // 64, 12 (cluster tails), or 8 (cluster 10)

  __shared__ __align__(16) unsigned short xtb[64*264]; // 33.8KB bf16 tile, row stride 528B
  __shared__ __align__(16) unsigned short swT[32*72];  // 4.6KB bf16 weights [sh][j], stride 144B
  __shared__ float psb[16*32];

  int wv = t >> 6, lane = t & 63;
  int Mt = wv & 3, Nt = wv >> 2;
  int l15 = lane & 15, kg = lane >> 4;
  int arow = Mt*16 + l15;
  uint4 bfr[8];
  const uint4* WQBF4 = (const uint4*)(ws + WQBF_OFF);
#pragma unroll
  for (int ks=0; ks<8; ++ks) bfr[ks] = WQBF4[(size_t)(Nt*8 + ks)*64 + lane];
  float cqv = ws[CQ_OFF + Nt*16 + l15];
  int shc = Nt*16 + l15;

  // stage 64 rows as bf16; rows >= N zero-filled (NaN-safe for pass2 MFMA)
  const float4* X4 = (const float4*)x;
#pragma unroll
  for (int k=0;k<8;k++){
    int f = t + k*512;
    int j = f >> 6, c4 = f & 63;
    float4 v = (n0 + j < N) ? X4[(size_t)(n0+j)*64 + c4] : make_float4(0.f,0.f,0.f,0.f);
    uint2 p;
    p.x = f2bf(v.x) | (f2bf(v.y) << 16);
    p.y = f2bf(v.z) | (f2bf(v.w) << 16);
    *(uint2*)(xtb + j*264 + c4*4) = p;
  }
  __syncthreads();

  // ---- pass 1: scores via 8x mfma_f32_16x16x32_bf16
  f32x4 acc1 = {0.f, 0.f, 0.f, 0.f};
#pragma unroll
  for (int ks=0; ks<8; ++ks){
    union { uint4 q; short8 v; } A, B;
    A.q = *(const uint4*)(xtb + arow*264 + ks*32 + kg*8);
    B.q = bfr[ks];
    acc1 = __builtin_amdgcn_mfma_f32_16x16x32_bf16(A.v, B.v, acc1, 0, 0, 0);
  }
  // epilogue: weights (bf16) -> swT[sh][j]; zero for j >= cnt; chunk sums.
  // C layout: col(sh)=lane&15, row(j)=kg*4+reg.
  {
    float ev[4];
    float s4 = 0.f;
#pragma unroll
    for (int r=0;r<4;r++){
      int jl = Mt*16 + kg*4 + r;
      float e = (jl < cnt) ? __expf(acc1[r] + cqv) : 0.f;
      ev[r] = e; s4 += e;
    }
    uint2 wp;
    wp.x = f2bf(ev[0]) | (f2bf(ev[1]) << 16);
    wp.y = f2bf(ev[2]) | (f2bf(ev[3]) << 16);
    *(uint2*)(swT + (size_t)shc*72 + Mt*16 + kg*4) = wp;
    psb[(Mt*4 + kg)*32 + shc] = s4;
  }
  __syncthreads();
  if (t < 32){
    float S = 0.f;
#pragma unroll
    for (int k=0;k<16;k++) S += psb[k*32 + t];
    unsafeAtomicAdd(ws + PS_OFF + (size_t)c*32 + t, S);
  }

  // ---- pass 2: O[sh][d] = sum_j w[j][sh]*x[j][d] via MFMA.
  int Mt2 = wv & 1, Nq = wv >> 1;
  union FR { uint4 q; short8 v; };
  FR a0, a1;
  a0.q = *(const uint4*)(swT + (size_t)(Mt2*16 + l15)*72 + kg*8);
  a1.q = *(const uint4*)(swT + (size_t)(Mt2*16 + l15)*72 + 32 + kg*8);
  unsigned xb = (unsigned)(size_t)&xtb[0];
  unsigned va = xb + (unsigned)(kg*4224 + (l15>>2)*528 + (l15&3)*8 + Nq*128);
  unsigned long long tr[4][2][2];
#pragma unroll
  for (int i=0;i<4;i++){
#pragma unroll
    for (int k2=0;k2<2;k2++){
      asm volatile("ds_read_b64_tr_b16 %0, %2 offset:%c3\n\t"
                   "ds_read_b64_tr_b16 %1, %2 offset:%c4"
                   : "=v"(tr[i][k2][0]), "=v"(tr[i][k2][1])
                   : "v"(va), "i"(i*32 + k2*16896), "i"(i*32 + k2*16896 + 2112));
    }
  }
  asm volatile("s_waitcnt lgkmcnt(0)" ::: "memory");
  __builtin_amdgcn_sched_barrier(0);
  f32x4 o[4] = {{0.f,0.f,0.f,0.f},{0.f,0.f,0.f,0.f},{0.f,0.f,0.f,0.f},{0.f,0.f,0.f,0.f}};
#pragma unroll
  for (int i=0;i<4;i++){
#pragma unroll
    for (int k2=0;k2<2;k2++){
      FR Bf;
      Bf.q.x = (unsigned)(tr[i][k2][0] & 0xffffffffULL);
      Bf.q.y = (unsigned)(tr[i][k2][0] >> 32);
      Bf.q.z = (unsigned)(tr[i][k2][1] & 0xffffffffULL);
      Bf.q.w = (unsigned)(tr[i][k2][1] >> 32);
      o[i] = __builtin_amdgcn_mfma_f32_16x16x32_bf16(k2 ? a1.v : a0.v, Bf.v, o[i], 0, 0, 0);
    }
  }
  // store partials as bf16: C layout col(d)=l15, row(sh)=kg*4+r
  unsigned short* pr = (unsigned short*)(ws + PART_OFF) + (size_t)b*8192;
#pragma unroll
  for (int i=0;i<4;i++){
    int dcol = Nq*64 + i*16 + l15;
#pragma unroll
    for (int r=0;r<4;r++)
      pr[(size_t)(Mt2*16 + kg*4 + r)*256 + dcol] = (unsigned short)f2bf(o[i][r]);
  }
}

// ---- KE2: sum bf16 chunk partials (f32 accum) / PS -> xw[c][sh][d]. 352 blocks.
__global__ __launch_bounds__(256) void ke2(float* __restrict__ ws){
  int b = blockIdx.x, t = threadIdx.x;
  int c = b >> 5, sh = b & 31;
  int nch = (c < 10) ? CPC : 1;
  int cb  = (c < 10) ? c*CPC : 520;
  float rden = 1.0f / ws[PS_OFF + (size_t)c*32 + sh];
  const unsigned short* part = (const unsigned short*)(ws + PART_OFF) + (size_t)sh*256 + t;
  float a = 0.f;
  for (int k=0;k<nch;k++)
    a += __uint_as_float(((unsigned)part[(size_t)(cb+k)*8192]) << 16);
  ws[XW_OFF + (size_t)c*8192 + (size_t)sh*256 + t] = a * rden;
}

// ---- KP: pooled per (c,s,eq). 176 blocks (R7-proven).
__global__ __launch_bounds__(256) void kp(float* __restrict__ ws,
    const float* __restrict__ Wv, const float* __restrict__ bv){
  int b = blockIdx.x; int c = b >> 4, rem = b & 15, s = rem >> 2, eq = rem & 3;
  int t = threadIdx.x, e64 = t & 63, dq = t >> 6;
  int e = eq*64 + e64, h = e >> 5;
  const float* xr = ws + XW_OFF + (size_t)c*8192 + (size_t)(s*8 + h)*256 + dq*64;
  const float* wv = Wv + (size_t)s*65536 + (size_t)(dq*64)*256 + e;
  float a = 0.f;
#pragma unroll 8
  for (int d=0; d<64; ++d) a = fmaf(wv[(size_t)d*256], xr[d], a);
  __shared__ float red[4][64];
  red[dq][e64] = a;
  __syncthreads();
  if (t < 64){
    float rcnt = (c < 10) ? (1.0f/(float)CS) : 0.125f;
    float p = (red[0][t]+red[1][t]+red[2][t]+red[3][t] + bv[s*256 + eq*64 + t]) * rcnt;
    ws[PL_OFF + (size_t)c*1024 + s*256 + eq*64 + t] = p;
  }
}

// ---- KO: out per (c,s,eq) = pooled @ Wo + bo. 176 blocks (R7-proven).
__global__ __launch_bounds__(256) void ko(float* __restrict__ ws,
    const float* __restrict__ Wo, const float* __restrict__ bo){
  int b = blockIdx.x; int c = b >> 4, rem = b & 15, s = rem >> 2, eq = rem & 3;
  int t = threadIdx.x, e64 = t & 63, dq = t >> 6;
  int e = eq*64 + e64;
  const float* pr = ws + PL_OFF + (size_t)c*1024 + s*256 + dq*64;
  const float* wo = Wo + (size_t)s*65536 + (size_t)(dq*64)*256 + e;
  float a = 0.f;
#pragma unroll 8
  for (int d=0; d<64; ++d) a = fmaf(wo[(size_t)d*256], pr[d], a);
  __shared__ float red[4][64];
  red[dq][e64] = a;
  __syncthreads();
  if (t < 64)
    ws[OL_OFF + (size_t)c*1024 + s*256 + eq*64 + t] =
      red[0][t]+red[1][t]+red[2][t]+red[3][t] + bo[s*256 + eq*64 + t];
}

// ---- KF1: h partials: block (c, fq, kq). 176 blocks (R7-proven).
__global__ __launch_bounds__(256) void kf1(const float* __restrict__ Wf1, float* __restrict__ ws){
  int b = blockIdx.x; int c = b >> 4, fq = (b >> 2) & 3, kq = b & 3;
  int t = threadIdx.x, f64 = t & 63, ks = t >> 6;
  const float* ol = ws + OL_OFF + (size_t)c*1024 + kq*256 + ks*64;
  const float* wf = Wf1 + (size_t)(kq*256 + ks*64)*256 + fq*64 + f64;
  float a = 0.f;
#pragma unroll 8
  for (int i=0; i<64; ++i) a = fmaf(wf[(size_t)i*256], ol[i], a);
  __shared__ float red[4][64];
  red[ks][f64] = a;
  __syncthreads();
  if (t < 64)
    ws[HP_OFF + (size_t)(c*4 + kq)*256 + fq*64 + t] = red[0][t]+red[1][t]+red[2][t]+red[3][t];
}

// ---- KF2B: (LN+GELU recomputed in-block from HP) -> Wf2 partials. 176 blocks (R11-proven).
__global__ __launch_bounds__(256) void kf2b(const float* __restrict__ Wf2, float* __restrict__ ws,
    const float* __restrict__ bf1, const float* __restrict__ lng, const float* __restrict__ lnb){
  int b = blockIdx.x; int c = b >> 4, gq = (b >> 2) & 3, kq = b & 3;
  int t = threadIdx.x;
  __shared__ float hl[256];
  __shared__ float rs1[4], rs2[4];
  float hacc = bf1[t];
#pragma unroll
  for (int q=0;q<4;q++) hacc += ws[HP_OFF + (size_t)(c*4+q)*256 + t];
  float s1 = hacc, s2v = hacc*hacc;
  for (int off=32; off>0; off>>=1){ s1 += __shfl_down(s1, off, 64); s2v += __shfl_down(s2v, off, 64); }
  int wid = t>>6, lane = t&63;
  if (lane==0){ rs1[wid]=s1; rs2[wid]=s2v; }
  __syncthreads();
  float S1 = rs1[0]+rs1[1]+rs1[2]+rs1[3];
  float S2 = rs2[0]+rs2[1]+rs2[2]+rs2[3];
  float mu = S1*(1.0f/256.0f);
  float var = S2*(1.0f/256.0f) - mu*mu;
  float rsig = rsqrtf(var + 1e-5f);
  float hn = (hacc - mu)*rsig*lng[t] + lnb[t];
  hl[t] = 0.5f*hn*(1.0f + erff(hn*0.70710678118654752f));   // exact GELU
  __syncthreads();
  int g64 = t & 63, ks = t >> 6;
  const float* hh = hl + kq*64 + ks*16;
  const float* wf = Wf2 + (size_t)(kq*64 + ks*16)*256 + gq*64 + g64;
  float a = 0.f;
#pragma unroll
  for (int i=0; i<16; ++i) a = fmaf(wf[(size_t)i*256], hh[i], a);
  __shared__ float red[4][64];
  red[ks][g64] = a;
  __syncthreads();
  if (t < 64)
    ws[FP_OFF + (size_t)(c*4 + kq)*256 + gq*64 + t] = red[0][t]+red[1][t]+red[2][t]+red[3][t];
}

// ---- KBC2: sum Wf2 partials + bf2 once per block, broadcast. 8192 blocks (R7-proven).
__global__ __launch_bounds__(256) void kbc2(const float* __restrict__ ws, float4* __restrict__ out,
                                            const float* __restrict__ bf2){
  unsigned bidx = blockIdx.x, t = threadIdx.x;
  unsigned idx = bidx*256u + t;
  unsigned c = (bidx*4u) / (unsigned)CS;   // 3276 % 4 == 0 -> one cluster per block
  __shared__ float4 row[64];
  if (t < 64){
    const float4* FP4 = (const float4*)(ws + FP_OFF);
    float4 s0 = FP4[(c*4+0)*64 + t];
    float4 s1 = FP4[(c*4+1)*64 + t];
    float4 s2 = FP4[(c*4+2)*64 + t];
    float4 s3 = FP4[(c*4+3)*64 + t];
    float4 bb = ((const float4*)bf2)[t];
    row[t] = make_float4(s0.x+s1.x+s2.x+s3.x+bb.x, s0.y+s1.y+s2.y+s3.y+bb.y,
                         s0.z+s1.z+s2.z+s3.z+bb.z, s0.w+s1.w+s2.w+s3.w+bb.w);
  }
  __syncthreads();
  out[idx] = row[t & 63u];
}

extern "C" void kernel_launch(void* const* d_in, const int* in_sizes, int n_in,
                              void* d_out, int out_size, void* d_ws, size_t ws_size,
                              hipStream_t stream) {
  const float* x   = (const float*)d_in[0];
  // d_in[1] edge_index, d_in[2] batch: unused by the reference computation
  const float* Wk  = (const float*)d_in[3];
  const float* bk  = (const float*)d_in[4];
  const float* Wv  = (const float*)d_in[5];
  const float* bv  = (const float*)d_in[6];
  const float* Wo  = (const float*)d_in[7];
  const float* bo  = (const float*)d_in[8];
  const float* pq  = (const float*)d_in[9];
  const float* Wf1 = (const float*)d_in[10];
  const float* bf1 = (const float*)d_in[11];
  const float* lng = (const float*)d_in[12];
  const float* lnb = (const float*)d_in[13];
  const float* Wf2 = (const float*)d_in[14];
  const float* bf2 = (const float*)d_in[15];
  float* ws = (float*)d_ws;
  float4* out = (float4*)d_out;

  hipLaunchKernelGGL(ka,    dim3(33),   dim3(256), 0, stream, Wk, bk, pq, ws);
  hipLaunchKernelGGL(kbd10, dim3(NB),   dim3(512), 0, stream, x, ws);
  hipLaunchKernelGGL(ke2,   dim3(352),  dim3(256), 0, stream, ws);
  hipLaunchKernelGGL(kp,    dim3(176),  dim3(256), 0, stream, ws, Wv, bv);
  hipLaunchKernelGGL(ko,    dim3(176),  dim3(256), 0, stream, ws, Wo, bo);
  hipLaunchKernelGGL(kf1,   dim3(176),  dim3(256), 0, stream, Wf1, ws);
  hipLaunchKernelGGL(kf2b,  dim3(176),  dim3(256), 0, stream, Wf2, ws, bf1, lng, lnb);
  hipLaunchKernelGGL(kbc2,  dim3(8192), dim3(256), 0, stream, ws, out, bf2);
}